// Round 5
// baseline (4035.253 us; speedup 1.0000x reference)
//
#include <hip/hip_runtime.h>

#define B_   8
#define N_   8192
#define CIN  64
#define COUT 128
#define M_   2048
#define K_   16

// ---------------------------------------------------------------------------
// 1) Pointwise MLP: h = relu( (x @ W^T - mean) * rsqrt(var+eps) * gamma + beta )
//    Continuous math — bf16-compare threshold tolerates f32 rounding here.
// ---------------------------------------------------------------------------
__global__ __launch_bounds__(256) void mlp_kernel(
    const float* __restrict__ x, const float* __restrict__ W,
    const float* __restrict__ gamma, const float* __restrict__ beta,
    const float* __restrict__ rmean, const float* __restrict__ rvar,
    float* __restrict__ h) {
  int tid = blockIdx.x * 256 + threadIdx.x;      // [0, B*N*COUT)
  int o   = tid & (COUT - 1);
  int row = tid >> 7;                            // b*N + n
  const float4* xr = (const float4*)(x + (size_t)row * CIN);
  const float4* wr = (const float4*)(W + (size_t)o * CIN);
  float acc = 0.f;
#pragma unroll
  for (int c = 0; c < CIN / 4; c++) {
    float4 a = xr[c], w = wr[c];
    acc += a.x * w.x + a.y * w.y + a.z * w.z + a.w * w.w;
  }
  float v = (acc - rmean[o]) * rsqrtf(rvar[o] + 1e-5f) * gamma[o] + beta[o];
  h[tid] = fmaxf(v, 0.f);
}

// ---------------------------------------------------------------------------
// 2) Farthest-point sampling — EXACT R1 form (f32, strict numpy order
//    ((dx^2+dy^2)+dz^2), no FMA, fminf, first-index argmax). Evidence this
//    matches the gold chain: two different f32 formulas (R1 no-FMA, R4 FMA)
//    give bit-identical results => chain robust at f32; f64 (R3) diverges.
// ---------------------------------------------------------------------------
__global__ __launch_bounds__(1024) void fps_kernel(
    const float* __restrict__ p, float* __restrict__ p_out) {
#pragma clang fp contract(off)
  __shared__ float px[N_], py[N_], pz[N_];
  __shared__ unsigned long long wred[2][16];
  __shared__ int idxHist[M_];

  const int b   = blockIdx.x;
  const int tid = threadIdx.x;
  const int wv  = tid >> 6;
  const int ln  = tid & 63;

  const float* pb = p + (size_t)b * N_ * 3;
  for (int i = tid; i < N_; i += 1024) {
    px[i] = pb[i * 3 + 0];
    py[i] = pb[i * 3 + 1];
    pz[i] = pb[i * 3 + 2];
  }
  if (tid == 0) idxHist[0] = 0;
  __syncthreads();

  float dist[8];
#pragma unroll
  for (int j = 0; j < 8; j++) dist[j] = __builtin_inff();

  int cur = 0;
  int buf = 0;
  for (int it = 1; it < M_; ++it) {
    const float lx = px[cur], ly = py[cur], lz = pz[cur];
    unsigned long long best = 0ull;
#pragma unroll
    for (int j = 0; j < 8; j++) {
      const int n = tid + j * 1024;
      float dx = px[n] - lx, dy = py[n] - ly, dz = pz[n] - lz;
      float d  = (dx * dx + dy * dy) + dz * dz;     // numpy sum order, no fma
      float dj = fminf(dist[j], d);
      dist[j]  = dj;
      unsigned long long key =
          ((unsigned long long)__float_as_uint(dj) << 32) |
          (unsigned)(N_ - 1 - n);                   // max key => max d, min n
      best = best > key ? best : key;
    }
#pragma unroll
    for (int off = 32; off >= 1; off >>= 1) {
      unsigned long long o = __shfl_xor(best, off);
      best = best > o ? best : o;
    }
    if (ln == 0) wred[buf][wv] = best;
    __syncthreads();
    unsigned long long m = wred[buf][0];
#pragma unroll
    for (int w = 1; w < 16; w++) {
      unsigned long long t = wred[buf][w];
      m = m > t ? m : t;
    }
    cur = N_ - 1 - (int)(unsigned)(m & 0xFFFFFFFFu);
    if (tid == 0) idxHist[it] = cur;
    buf ^= 1;
  }
  __syncthreads();

  float* po = p_out + (size_t)b * M_ * 3;
  for (int mi = tid; mi < M_; mi += 1024) {
    int id = idxHist[mi];
    po[mi * 3 + 0] = px[id];
    po[mi * 3 + 1] = py[id];
    po[mi * 3 + 2] = pz[id];
  }
}

// ---------------------------------------------------------------------------
// 3) KNN — replicate GOLD'S f32 d2 bits, then exact top-16 on those values.
//    Gold (numpy/BLAS f32): sq,sn = sequential no-FMA 3-term sums;
//    dot = BLAS k-ascending FMA chain fma(z, fma(y, x*x)); then
//    d2 = (sq + sn) - 2*dot, all f32. Selection boundaries where the
//    expansion-form cancellation noise (~1e-6) decides the winner are now
//    decided identically to gold. Lowest-index tie-break == top_k.
// ---------------------------------------------------------------------------
__global__ __launch_bounds__(64) void knn_kernel(
    const float* __restrict__ p, const float* __restrict__ p_out,
    const float* __restrict__ h, float* __restrict__ y) {
#pragma clang fp contract(off)
  __shared__ float d2s[N_];      // 32 KB
  __shared__ int win[K_];

  const int q    = blockIdx.x;        // b*M + m
  const int b    = q >> 11;           // M_ = 2048
  const int lane = threadIdx.x;

  const float qx = p_out[q * 3 + 0];
  const float qy = p_out[q * 3 + 1];
  const float qz = p_out[q * 3 + 2];
  const float sq = (qx * qx + qy * qy) + qz * qz;   // numpy sum, no fma

  const float* pb = p + (size_t)b * N_ * 3;
  for (int s = 0; s < N_ / 64; s++) {
    const int n = s * 64 + lane;
    float xx = pb[n * 3 + 0], yy = pb[n * 3 + 1], zz = pb[n * 3 + 2];
    float sn  = (xx * xx + yy * yy) + zz * zz;      // numpy sum, no fma
    float dot = __builtin_fmaf(qz, zz,
                __builtin_fmaf(qy, yy, qx * xx));   // BLAS fma chain, k asc
    d2s[n] = (sq + sn) - 2.0f * dot;
  }
  __syncthreads();

  int myNbr = 0;
  for (int k = 0; k < K_; k++) {
    float bv = __builtin_inff();
    int   bi = 0;
    for (int s = 0; s < N_ / 64; s++) {
      const int n = s * 64 + lane;
      float v = d2s[n];
      if (v < bv) { bv = v; bi = n; }   // strict < keeps lowest n within lane
    }
    // monotonic float->uint map (d2 can be slightly negative numerically)
    unsigned u = __float_as_uint(bv);
    u ^= (unsigned)((int)u >> 31) | 0x80000000u;
    unsigned long long key = ((unsigned long long)u << 32) | (unsigned)bi;
#pragma unroll
    for (int off = 32; off >= 1; off >>= 1) {
      unsigned long long o = __shfl_xor(key, off);
      key = key < o ? key : o;          // min d2, tie -> min index (stable)
    }
    const int n = (int)(unsigned)(key & 0xFFFFFFFFu);
    if (lane == k) myNbr = n;
    if (lane == (n & 63)) d2s[n] = __builtin_inff();
    __syncthreads();
  }

  if (lane < K_) win[lane] = myNbr;
  __syncthreads();

  // fused gather + max-pool over K: lane handles channels [2*lane, 2*lane+1]
  const float* hb = h + (size_t)b * N_ * COUT;
  float2 acc = make_float2(-__builtin_inff(), -__builtin_inff());
#pragma unroll
  for (int k = 0; k < K_; k++) {
    const int n = win[k];
    float2 v = *(const float2*)(hb + (size_t)n * COUT + lane * 2);
    acc.x = fmaxf(acc.x, v.x);
    acc.y = fmaxf(acc.y, v.y);
  }
  *(float2*)(y + (size_t)q * COUT + lane * 2) = acc;
}

// ---------------------------------------------------------------------------
extern "C" void kernel_launch(void* const* d_in, const int* in_sizes, int n_in,
                              void* d_out, int out_size, void* d_ws, size_t ws_size,
                              hipStream_t stream) {
  const float* x     = (const float*)d_in[0];
  const float* p     = (const float*)d_in[1];
  const float* W     = (const float*)d_in[2];
  const float* gamma = (const float*)d_in[3];
  const float* beta  = (const float*)d_in[4];
  const float* rmean = (const float*)d_in[5];
  const float* rvar  = (const float*)d_in[6];

  float* y     = (float*)d_out;                       // (B, M, COUT)
  float* p_out = y + (size_t)B_ * M_ * COUT;          // (B, M, 3)
  float* h     = (float*)d_ws;                        // (B, N, COUT) scratch

  mlp_kernel<<<(B_ * N_ * COUT) / 256, 256, 0, stream>>>(
      x, W, gamma, beta, rmean, rvar, h);
  fps_kernel<<<B_, 1024, 0, stream>>>(p, p_out);
  knn_kernel<<<B_ * M_, 64, 0, stream>>>(p, p_out, h, y);
}

// Round 6
// 3085.282 us; speedup vs baseline: 1.3079x; 1.3079x over previous
//
#include <hip/hip_runtime.h>

#define B_   8
#define N_   8192
#define CIN  64
#define COUT 128
#define M_   2048
#define K_   16

// ---------------------------------------------------------------------------
// 1) Pointwise MLP: h = relu( (x @ W^T - mean) * rsqrt(var+eps) * gamma + beta )
// ---------------------------------------------------------------------------
__global__ __launch_bounds__(256) void mlp_kernel(
    const float* __restrict__ x, const float* __restrict__ W,
    const float* __restrict__ gamma, const float* __restrict__ beta,
    const float* __restrict__ rmean, const float* __restrict__ rvar,
    float* __restrict__ h) {
  int tid = blockIdx.x * 256 + threadIdx.x;      // [0, B*N*COUT)
  int o   = tid & (COUT - 1);
  int row = tid >> 7;                            // b*N + n
  const float4* xr = (const float4*)(x + (size_t)row * CIN);
  const float4* wr = (const float4*)(W + (size_t)o * CIN);
  float acc = 0.f;
#pragma unroll
  for (int c = 0; c < CIN / 4; c++) {
    float4 a = xr[c], w = wr[c];
    acc += a.x * w.x + a.y * w.y + a.z * w.z + a.w * w.w;
  }
  float v = (acc - rmean[o]) * rsqrtf(rvar[o] + 1e-5f) * gamma[o] + beta[o];
  h[tid] = fmaxf(v, 0.f);
}

// ---------------------------------------------------------------------------
// 2) FPS — numerics IDENTICAL to the R5-passing kernel (f32, strict numpy
//    order ((dx^2+dy^2)+dz^2) no-FMA, fminf, u64-packed argmax with
//    (N-1-n) first-index tie-break). Structural changes only:
//    * 512 threads; each thread's 16 points live in REGISTERS (no LDS
//      coord reads in the hot loop).
//    * reduce: per-thread best -> cand[512] -> wave 0 only reduces
//      (8 strided u64 reads + butterfly) -> lane 0 reads winner coords
//      from interleaved LDS copy, writes float4 broadcast slot and
//      streams p_out[it] directly (no idxHist, no final gather).
//    DS wave-instructions per iteration: ~900 -> ~40.
// ---------------------------------------------------------------------------
#define FTH 512
#define FPT 16   // points per thread = N_/FTH

__global__ __launch_bounds__(512) void fps_kernel(
    const float* __restrict__ p, float* __restrict__ p_out) {
#pragma clang fp contract(off)
  __shared__ float pc[N_ * 3];                  // 96 KB, interleaved xyz
  __shared__ unsigned long long cand[FTH];      // 4 KB
  __shared__ float4 bcast;                      // winner coords broadcast

  const int b   = blockIdx.x;
  const int tid = threadIdx.x;
  const int wv  = tid >> 6;
  const int ln  = tid & 63;

  // stage p[b] into LDS (contiguous float4 copy: 24576 floats = 6144 f4)
  const float4* pb4 = (const float4*)(p + (size_t)b * N_ * 3);
  float4* pc4 = (float4*)pc;
#pragma unroll
  for (int i = 0; i < (N_ * 3 / 4) / FTH; i++)
    pc4[tid + i * FTH] = pb4[tid + i * FTH];
  __syncthreads();

  if (tid == 0) {
    float x0 = pc[0], y0 = pc[1], z0 = pc[2];
    bcast = make_float4(x0, y0, z0, 0.f);
    float* po = p_out + (size_t)b * M_ * 3;
    po[0] = x0; po[1] = y0; po[2] = z0;         // sample 0 = point 0
  }

  // my 16 points -> registers (n = tid + k*512)
  float X[FPT], Y[FPT], Z[FPT], D[FPT];
#pragma unroll
  for (int k = 0; k < FPT; k++) {
    int n3 = (tid + k * FTH) * 3;
    X[k] = pc[n3 + 0]; Y[k] = pc[n3 + 1]; Z[k] = pc[n3 + 2];
    D[k] = __builtin_inff();
  }
  __syncthreads();

  for (int it = 1; it < M_; ++it) {
    float4 c = bcast;                           // 1 LDS broadcast read/wave
    float bd = -1.0f; int bk = 0;
#pragma unroll
    for (int k = 0; k < FPT; k++) {
      float dx = X[k] - c.x, dy = Y[k] - c.y, dz = Z[k] - c.z;
      float d  = (dx * dx + dy * dy) + dz * dz; // numpy sum order, no fma
      float dm = fminf(D[k], d);
      D[k] = dm;
      if (dm > bd) { bd = dm; bk = k; }         // strict > keeps min k (min n)
    }
    int n = tid + (bk << 9);                    // bk*512
    cand[tid] = ((unsigned long long)__float_as_uint(bd) << 32) |
                (unsigned)(N_ - 1 - n);         // max key => max d, min n
    __syncthreads();                            // A: cand ready, bcast consumed
    if (wv == 0) {
      unsigned long long m = cand[ln];
#pragma unroll
      for (int k2 = 1; k2 < FTH / 64; k2++) {
        unsigned long long t = cand[ln + (k2 << 6)];
        m = t > m ? t : m;
      }
#pragma unroll
      for (int off = 32; off >= 1; off >>= 1) {
        unsigned long long o = __shfl_xor(m, off);
        m = o > m ? o : m;
      }
      if (ln == 0) {
        int nw = N_ - 1 - (int)(unsigned)(m & 0xFFFFFFFFu);
        float x = pc[nw * 3], y = pc[nw * 3 + 1], z = pc[nw * 3 + 2];
        bcast = make_float4(x, y, z, 0.f);
        float* po = p_out + ((size_t)b * M_ + it) * 3;
        po[0] = x; po[1] = y; po[2] = z;        // stream p_out directly
      }
    }
    __syncthreads();                            // B: new bcast visible
  }
}

// ---------------------------------------------------------------------------
// 3) KNN — d2 values and selection semantics IDENTICAL to R5 (f32
//    expansion form, sq/sn no-FMA sums, BLAS k-ascending FMA-chain dot;
//    exact global min with first-index tie-break, mark-INF extraction).
//    Structural change: 4 waves per query. Wave w scans quarter
//    [w*2048, (w+1)*2048) at stride 64 (conflict-free), candidates packed
//    u64 (mono32(d2)<<32 | n) -> wave-min butterfly (order-independent,
//    ties resolve to min n automatically) -> thread 0 combines 4 partials.
//    Epilogue: 4 neighbors/wave, float2/lane, LDS combine.
// ---------------------------------------------------------------------------
__global__ __launch_bounds__(256) void knn_kernel(
    const float* __restrict__ p, const float* __restrict__ p_out,
    const float* __restrict__ h, float* __restrict__ y) {
#pragma clang fp contract(off)
  __shared__ float d2s[N_];                     // 32 KB
  __shared__ unsigned long long part[4];
  __shared__ int win[K_];
  __shared__ float2 pmax[4][64];

  const int q    = blockIdx.x;                  // b*M + m
  const int b    = q >> 11;                     // M_ = 2048
  const int t    = threadIdx.x;
  const int w    = t >> 6;
  const int lane = t & 63;

  const float qx = p_out[q * 3 + 0];
  const float qy = p_out[q * 3 + 1];
  const float qz = p_out[q * 3 + 2];
  const float sq = (qx * qx + qy * qy) + qz * qz;   // numpy sum, no fma

  const float* pb = p + (size_t)b * N_ * 3;
#pragma unroll
  for (int j = 0; j < N_ / 256; j++) {
    const int n = t + j * 256;                  // coalesced
    float xx = pb[n * 3 + 0], yy = pb[n * 3 + 1], zz = pb[n * 3 + 2];
    float sn  = (xx * xx + yy * yy) + zz * zz;  // numpy sum, no fma
    float dot = __builtin_fmaf(qz, zz,
                __builtin_fmaf(qy, yy, qx * xx)); // BLAS fma chain, k asc
    d2s[n] = (sq + sn) - 2.0f * dot;
  }
  __syncthreads();

  const int base = (w << 11) + lane;            // w*2048 + lane
  for (int k = 0; k < K_; k++) {
    float bv = __builtin_inff();
    int   bj = 0;
#pragma unroll
    for (int j = 0; j < 32; j++) {
      float v = d2s[base + (j << 6)];
      if (v < bv) { bv = v; bj = j; }           // strict < -> first (min) n
    }
    // monotone f32->u32 (d2 can be slightly negative), then u64 key with n:
    // min key == (min d2, then min n) — fully order-independent.
    unsigned u = __float_as_uint(bv);
    u ^= (unsigned)((int)u >> 31) | 0x80000000u;
    unsigned long long key =
        ((unsigned long long)u << 32) | (unsigned)(base + (bj << 6));
#pragma unroll
    for (int off = 32; off >= 1; off >>= 1) {
      unsigned long long o = __shfl_xor(key, off);
      key = key < o ? key : o;
    }
    if (lane == 0) part[w] = key;
    __syncthreads();
    if (t == 0) {
      unsigned long long m = part[0];
      m = part[1] < m ? part[1] : m;
      m = part[2] < m ? part[2] : m;
      m = part[3] < m ? part[3] : m;
      int nk = (int)(unsigned)(m & 0xFFFFFFFFu);
      win[k] = nk;
      d2s[nk] = __builtin_inff();               // extract
    }
    __syncthreads();
  }

  // epilogue: wave w max-pools neighbors [4w, 4w+4); lane covers 2 channels
  const float* hb = h + (size_t)b * N_ * COUT;
  float2 acc = make_float2(-__builtin_inff(), -__builtin_inff());
#pragma unroll
  for (int i = 0; i < 4; i++) {
    const int n = win[(w << 2) + i];
    float2 v = *(const float2*)(hb + (size_t)n * COUT + lane * 2);
    acc.x = fmaxf(acc.x, v.x);
    acc.y = fmaxf(acc.y, v.y);
  }
  pmax[w][lane] = acc;
  __syncthreads();
  if (w == 0) {
    float2 a0 = pmax[0][lane], a1 = pmax[1][lane];
    float2 a2 = pmax[2][lane], a3 = pmax[3][lane];
    float2 r;
    r.x = fmaxf(fmaxf(a0.x, a1.x), fmaxf(a2.x, a3.x));
    r.y = fmaxf(fmaxf(a0.y, a1.y), fmaxf(a2.y, a3.y));
    *(float2*)(y + (size_t)q * COUT + lane * 2) = r;
  }
}

// ---------------------------------------------------------------------------
extern "C" void kernel_launch(void* const* d_in, const int* in_sizes, int n_in,
                              void* d_out, int out_size, void* d_ws, size_t ws_size,
                              hipStream_t stream) {
  const float* x     = (const float*)d_in[0];
  const float* p     = (const float*)d_in[1];
  const float* W     = (const float*)d_in[2];
  const float* gamma = (const float*)d_in[3];
  const float* beta  = (const float*)d_in[4];
  const float* rmean = (const float*)d_in[5];
  const float* rvar  = (const float*)d_in[6];

  float* y     = (float*)d_out;                       // (B, M, COUT)
  float* p_out = y + (size_t)B_ * M_ * COUT;          // (B, M, 3)
  float* h     = (float*)d_ws;                        // (B, N, COUT) scratch

  mlp_kernel<<<(B_ * N_ * COUT) / 256, 256, 0, stream>>>(
      x, W, gamma, beta, rmean, rvar, h);
  fps_kernel<<<B_, FTH, 0, stream>>>(p, p_out);
  knn_kernel<<<B_ * M_, 256, 0, stream>>>(p, p_out, h, y);
}

// Round 7
// 2872.581 us; speedup vs baseline: 1.4047x; 1.0740x over previous
//
#include <hip/hip_runtime.h>

#define B_   8
#define N_   8192
#define CIN  64
#define COUT 128
#define M_   2048
#define K_   16

// ---------------------------------------------------------------------------
// 1) Pointwise MLP: h = relu( (x @ W^T - mean) * rsqrt(var+eps) * gamma + beta )
// ---------------------------------------------------------------------------
__global__ __launch_bounds__(256) void mlp_kernel(
    const float* __restrict__ x, const float* __restrict__ W,
    const float* __restrict__ gamma, const float* __restrict__ beta,
    const float* __restrict__ rmean, const float* __restrict__ rvar,
    float* __restrict__ h) {
  int tid = blockIdx.x * 256 + threadIdx.x;      // [0, B*N*COUT)
  int o   = tid & (COUT - 1);
  int row = tid >> 7;                            // b*N + n
  const float4* xr = (const float4*)(x + (size_t)row * CIN);
  const float4* wr = (const float4*)(W + (size_t)o * CIN);
  float acc = 0.f;
#pragma unroll
  for (int c = 0; c < CIN / 4; c++) {
    float4 a = xr[c], w = wr[c];
    acc += a.x * w.x + a.y * w.y + a.z * w.z + a.w * w.w;
  }
  float v = (acc - rmean[o]) * rsqrtf(rvar[o] + 1e-5f) * gamma[o] + beta[o];
  h[tid] = fmaxf(v, 0.f);
}

// ---------------------------------------------------------------------------
// 2) FPS — numerics identical to the R5/R6-passing chain (f32, strict numpy
//    order ((dx^2+dy^2)+dz^2) no-FMA, fminf, u64 (d<<32)|(N-1-n) argmax =
//    first-index tie-break). Structural changes vs R6:
//    * NO global stores in the loop (idxHist in LDS; p_out written at end)
//      -> no s_waitcnt vmcnt(0) drain before s_barrier each iteration.
//    * symmetric decode: per-wave butterfly -> wred[buf][8] -> EVERY thread
//      reads 8 keys + winner coords itself; center kept in registers.
//    * ONE barrier per iteration (double-buffered wred).
// ---------------------------------------------------------------------------
#define FTH 512
#define FPT 16   // points per thread = N_/FTH

__global__ __launch_bounds__(512) void fps_kernel(
    const float* __restrict__ p, float* __restrict__ p_out) {
#pragma clang fp contract(off)
  __shared__ float pc[N_ * 3];                  // 96 KB, interleaved xyz
  __shared__ unsigned long long wred[2][8];
  __shared__ int idxHist[M_];                   // 8 KB

  const int b   = blockIdx.x;
  const int tid = threadIdx.x;
  const int wv  = tid >> 6;
  const int ln  = tid & 63;

  // stage p[b] into LDS (contiguous float4 copy)
  const float4* pb4 = (const float4*)(p + (size_t)b * N_ * 3);
  float4* pc4 = (float4*)pc;
#pragma unroll
  for (int i = 0; i < (N_ * 3 / 4) / FTH; i++)
    pc4[tid + i * FTH] = pb4[tid + i * FTH];
  if (tid == 0) idxHist[0] = 0;
  __syncthreads();

  // current center in registers (sample 0 = point 0)
  float cx = pc[0], cy = pc[1], cz = pc[2];

  // my 16 points -> registers (n = tid + k*512); pc stays for winner lookup
  float X[FPT], Y[FPT], Z[FPT], D[FPT];
#pragma unroll
  for (int k = 0; k < FPT; k++) {
    int n3 = (tid + k * FTH) * 3;
    X[k] = pc[n3 + 0]; Y[k] = pc[n3 + 1]; Z[k] = pc[n3 + 2];
    D[k] = __builtin_inff();
  }

  int buf = 0;
  for (int it = 1; it < M_; ++it) {
    float bd = -1.0f; int bk = 0;
#pragma unroll
    for (int k = 0; k < FPT; k++) {
      float dx = X[k] - cx, dy = Y[k] - cy, dz = Z[k] - cz;
      float d  = (dx * dx + dy * dy) + dz * dz; // numpy sum order, no fma
      float dm = fminf(D[k], d);
      D[k] = dm;
      if (dm > bd) { bd = dm; bk = k; }         // strict > keeps min k (min n)
    }
    int n = tid + (bk << 9);                    // bk*512
    unsigned long long key =
        ((unsigned long long)__float_as_uint(bd) << 32) |
        (unsigned)(N_ - 1 - n);                 // max key => max d, min n
#pragma unroll
    for (int off = 32; off >= 1; off >>= 1) {
      unsigned long long o = __shfl_xor(key, off);
      key = key > o ? key : o;
    }
    if (ln == 0) wred[buf][wv] = key;
    __syncthreads();                            // the ONLY barrier per iter
    unsigned long long m = wred[buf][0];
#pragma unroll
    for (int w = 1; w < 8; w++) {
      unsigned long long t = wred[buf][w];
      m = t > m ? t : m;                        // ties impossible (unique n)
    }
    const int nw = N_ - 1 - (int)(unsigned)(m & 0xFFFFFFFFu);
    cx = pc[nw * 3]; cy = pc[nw * 3 + 1]; cz = pc[nw * 3 + 2];  // broadcast
    if (tid == 0) idxHist[it] = nw;
    buf ^= 1;
  }
  __syncthreads();

  // write p_out once, at the end (outside the serial loop)
  float* po = p_out + (size_t)b * M_ * 3;
  for (int mi = tid; mi < M_; mi += FTH) {
    int id = idxHist[mi];
    po[mi * 3 + 0] = pc[id * 3 + 0];
    po[mi * 3 + 1] = pc[id * 3 + 1];
    po[mi * 3 + 2] = pc[id * 3 + 2];
  }
}

// ---------------------------------------------------------------------------
// 3) KNN — d2 values & selection semantics identical to R5/R6 (f32 expansion
//    form, sq/sn no-FMA sums, BLAS k-ascending FMA-chain dot; repeated global
//    (d2,index)-lexicographic min extraction == top_k set + tie-break).
//    Structural changes:
//    * d2 kept in REGISTERS (32/lane), no LDS d2s, no INF marking.
//    * per-lane sorted top-3 cache (packed u64 keys); pop-on-win with
//      per-lane extraction mask; register rescan only when cache empties
//      (needs >=3 wins on one lane: <1% of blocks).
//    * ONE barrier per round (double-buffered part[2][4]); all-thread decode.
//    * gather+max-pool FUSED into rounds: wave k>>2 gathers neighbor k,
//      load latency overlaps later rounds.
// ---------------------------------------------------------------------------
#define UMAXK 0xFFFFFFFFFFFFFFFFull

__global__ __launch_bounds__(256) void knn_kernel(
    const float* __restrict__ p, const float* __restrict__ p_out,
    const float* __restrict__ h, float* __restrict__ y) {
#pragma clang fp contract(off)
  __shared__ unsigned long long part[2][4];
  __shared__ float2 pmax[4][64];

  const int q    = blockIdx.x;                  // b*M + m
  const int b    = q >> 11;                     // M_ = 2048
  const int t    = threadIdx.x;
  const int w    = t >> 6;
  const int lane = t & 63;

  const float qx = p_out[q * 3 + 0];
  const float qy = p_out[q * 3 + 1];
  const float qz = p_out[q * 3 + 2];
  const float sq = (qx * qx + qy * qy) + qz * qz;   // numpy sum, no fma

  const float* pb = p + (size_t)b * N_ * 3;
  float dv[32];
  unsigned long long k1 = UMAXK, k2 = UMAXK, k3 = UMAXK;
#pragma unroll
  for (int j = 0; j < 32; j++) {
    const int n = t + (j << 8);                 // coalesced across lanes
    float xx = pb[n * 3 + 0], yy = pb[n * 3 + 1], zz = pb[n * 3 + 2];
    float sn  = (xx * xx + yy * yy) + zz * zz;  // numpy sum, no fma
    float dot = __builtin_fmaf(qz, zz,
                __builtin_fmaf(qy, yy, qx * xx)); // BLAS fma chain, k asc
    float d2 = (sq + sn) - 2.0f * dot;
    dv[j] = d2;
    unsigned u = __float_as_uint(d2);
    u ^= (unsigned)((int)u >> 31) | 0x80000000u;  // monotone f32->u32
    unsigned long long key = ((unsigned long long)u << 32) | (unsigned)n;
    if (key < k1)      { k3 = k2; k2 = k1; k1 = key; }
    else if (key < k2) { k3 = k2; k2 = key; }
    else if (key < k3) { k3 = key; }
  }
  int count = 3;
  unsigned mask = 0;

  const float* hb = h + (size_t)b * N_ * COUT;
  float2 acc = make_float2(-__builtin_inff(), -__builtin_inff());

  for (int k = 0; k < K_; k++) {
    const int pbuf = k & 1;
    unsigned long long key = (count > 0) ? k1 : UMAXK;
#pragma unroll
    for (int off = 32; off >= 1; off >>= 1) {
      unsigned long long o = __shfl_xor(key, off);
      key = key < o ? key : o;                  // unique n -> no ties
    }
    if (lane == 0) part[pbuf][w] = key;
    __syncthreads();                            // the ONLY barrier per round
    unsigned long long m = part[pbuf][0];
    m = part[pbuf][1] < m ? part[pbuf][1] : m;
    m = part[pbuf][2] < m ? part[pbuf][2] : m;
    m = part[pbuf][3] < m ? part[pbuf][3] : m;
    const int nstar = (int)(unsigned)(m & 0xFFFFFFFFu);

    // fused gather: wave (k>>2) max-pools neighbor k (latency overlaps rounds)
    if ((k >> 2) == w) {
      float2 v = *(const float2*)(hb + (size_t)nstar * COUT + lane * 2);
      acc.x = fmaxf(acc.x, v.x);
      acc.y = fmaxf(acc.y, v.y);
    }

    // pop if the winner is my cached min (unique index => exactly one lane)
    if (count > 0 && (int)(unsigned)(k1 & 0xFFFFFFFFu) == nstar) {
      mask |= 1u << (nstar >> 8);               // slot j = n>>8 (n%256 == t)
      k1 = k2; k2 = k3; k3 = UMAXK; count--;
      if (count == 0 && k < K_ - 1) {           // rare register rescan
        k1 = k2 = k3 = UMAXK;
#pragma unroll
        for (int j = 0; j < 32; j++) {
          if (!((mask >> j) & 1u)) {
            unsigned u = __float_as_uint(dv[j]);
            u ^= (unsigned)((int)u >> 31) | 0x80000000u;
            unsigned long long kk =
                ((unsigned long long)u << 32) | (unsigned)(t + (j << 8));
            if (kk < k1)      { k3 = k2; k2 = k1; k1 = kk; }
            else if (kk < k2) { k3 = k2; k2 = kk; }
            else if (kk < k3) { k3 = kk; }
          }
        }
        count = 3;
      }
    }
  }

  // combine the 4 wave partials
  pmax[w][lane] = acc;
  __syncthreads();
  if (w == 0) {
    float2 a0 = pmax[0][lane], a1 = pmax[1][lane];
    float2 a2 = pmax[2][lane], a3 = pmax[3][lane];
    float2 r;
    r.x = fmaxf(fmaxf(a0.x, a1.x), fmaxf(a2.x, a3.x));
    r.y = fmaxf(fmaxf(a0.y, a1.y), fmaxf(a2.y, a3.y));
    *(float2*)(y + (size_t)q * COUT + lane * 2) = r;
  }
}

// ---------------------------------------------------------------------------
extern "C" void kernel_launch(void* const* d_in, const int* in_sizes, int n_in,
                              void* d_out, int out_size, void* d_ws, size_t ws_size,
                              hipStream_t stream) {
  const float* x     = (const float*)d_in[0];
  const float* p     = (const float*)d_in[1];
  const float* W     = (const float*)d_in[2];
  const float* gamma = (const float*)d_in[3];
  const float* beta  = (const float*)d_in[4];
  const float* rmean = (const float*)d_in[5];
  const float* rvar  = (const float*)d_in[6];

  float* y     = (float*)d_out;                       // (B, M, COUT)
  float* p_out = y + (size_t)B_ * M_ * COUT;          // (B, M, 3)
  float* h     = (float*)d_ws;                        // (B, N, COUT) scratch

  mlp_kernel<<<(B_ * N_ * COUT) / 256, 256, 0, stream>>>(
      x, W, gamma, beta, rmean, rvar, h);
  fps_kernel<<<B_, FTH, 0, stream>>>(p, p_out);
  knn_kernel<<<B_ * M_, 256, 0, stream>>>(p, p_out, h, y);
}